// Round 4
// baseline (213.366 us; speedup 1.0000x reference)
//
#include <hip/hip_runtime.h>

// SigMMDLoss, algebraically flattened (see round-1/2 derivation):
//   A  = p[4095]-p[0]; S3 = p[4095] - SP_row/n; S4 = (A^2+S6)/2;
//   S6 = sum d^2; S8 = sum d^3;  time-only features cancel.
// Global sums per array: SP (sum p excl last col), D2, D3,
// G1 = sum_rows A, G2 = sum_rows A^2, G3 = sum_rows p[4095].
// out = sum_q ((F_q^real - F_q^gen)/B)^2.
//
// Round-7 = round-6 design, compile-fixed (ACC macro's param `x` was
// textually replacing the .x/.y/.z/.w member tokens; now a lambda).
// Persistent streaming: grid = 2048 blocks = 8192 waves = exactly one
// full-occupancy round. One wave owns one full row as 4 quarter-row
// chunks with 2-deep register double-buffering so vector loads are
// always in flight. Carry/p0/p4095 all in-register; sign folded into
// the partial write.

constexpr int T_LEN = 4096;
constexpr int B_ROWS = 4096;
constexpr int NQ = 6;                   // sp, d2, d3, g1, g2, g3
constexpr int NBLK = 2048;

__global__ __launch_bounds__(256, 8) void sig_stream(
    const float* __restrict__ real, const float* __restrict__ gen,
    double* __restrict__ P) {
  const int tid = threadIdx.x;
  const int lane = tid & 63;
  const int wid = tid >> 6;
  const int w = blockIdx.x * 4 + wid;       // wave id in [0, 8192)
  const int which = w >> 12;                // 0: real rows, 1: gen rows
  const int row = w & 4095;
  const float* __restrict__ rp = (which ? gen : real) + (size_t)row * T_LEN;
  const float4* __restrict__ q4 = reinterpret_cast<const float4*>(rp);

  float sp = 0.f, s2 = 0.f, s3 = 0.f;
  float carry;                              // predecessor of next chunk's elem 0
  const int rsrc = (lane + 63) & 63;        // rotate-by-1 source lane

  // Accumulate one float4 given the predecessor of its first element.
  auto acc1 = [&](const float4& v, float px) {
    const float d0 = v.x - px;
    const float d1 = v.y - v.x;
    const float d2 = v.z - v.y;
    const float d3 = v.w - v.z;
    const float e0 = d0 * d0, e1 = d1 * d1, e2 = d2 * d2, e3 = d3 * d3;
    s2 += (e0 + e1) + (e2 + e3);
    s3 += (e0 * d0 + e1 * d1) + (e2 * d2 + e3 * d3);
    sp += (v.x + v.y) + (v.z + v.w);
  };

  // Process one quarter-row (4 float4/lane). Predecessors via independent
  // rotate shuffles; lane 0 patches from the previous float4's lane-63
  // value (rot[j-1]) or the inter-chunk carry.
  auto proc = [&](const float4& x0, const float4& x1, const float4& x2,
                  const float4& x3) {
    const float r0 = __shfl(x0.w, rsrc, 64);
    const float r1 = __shfl(x1.w, rsrc, 64);
    const float r2 = __shfl(x2.w, rsrc, 64);
    const float r3 = __shfl(x3.w, rsrc, 64);
    const float px0 = (lane == 0) ? carry : r0;
    const float px1 = (lane == 0) ? r0 : r1;
    const float px2 = (lane == 0) ? r1 : r2;
    const float px3 = (lane == 0) ? r2 : r3;
    acc1(x0, px0);
    acc1(x1, px1);
    acc1(x2, px2);
    acc1(x3, px3);
    carry = __shfl(x3.w, 63, 64);           // last element of this chunk
  };

  // Software pipeline: issue chunk k+1 before processing chunk k.
  float4 a0 = q4[lane], a1 = q4[64 + lane], a2 = q4[128 + lane],
         a3 = q4[192 + lane];
  float4 b0 = q4[256 + lane], b1 = q4[320 + lane], b2 = q4[384 + lane],
         b3 = q4[448 + lane];
  carry = __shfl(a0.x, 0, 64);              // p[row][0]; makes d0 = 0 at t=0
  const float p0 = carry;
  proc(a0, a1, a2, a3);
  a0 = q4[512 + lane]; a1 = q4[576 + lane]; a2 = q4[640 + lane];
  a3 = q4[704 + lane];
  proc(b0, b1, b2, b3);
  b0 = q4[768 + lane]; b1 = q4[832 + lane]; b2 = q4[896 + lane];
  b3 = q4[960 + lane];
  proc(a0, a1, a2, a3);
  const float plast_reg = b3.w;             // lane 63 holds p[4095]
  proc(b0, b1, b2, b3);

  // Row-level features on lane 63 (holds p[4095] = plast_reg).
  double g1 = 0., g2 = 0., g3 = 0.;
  if (lane == 63) {
    const float plast = plast_reg;
    sp -= plast;                            // SP excludes last column
    const double A = (double)plast - (double)p0;
    g1 = A;
    g2 = A * A;
    g3 = (double)plast;
  }

  // Wave reduce (fp32 streams; g* already single-lane).
#pragma unroll
  for (int o = 32; o; o >>= 1) {
    sp += __shfl_down(sp, o, 64);
    s2 += __shfl_down(s2, o, 64);
    s3 += __shfl_down(s3, o, 64);
  }

  const double sgn = which ? -1.0 : 1.0;    // fold real-minus-gen here
  __shared__ double sred[4][NQ];
  if (lane == 0) {
    sred[wid][0] = sgn * (double)sp;
    sred[wid][1] = sgn * (double)s2;
    sred[wid][2] = sgn * (double)s3;
  }
  if (lane == 63) {
    sred[wid][3] = sgn * g1;
    sred[wid][4] = sgn * g2;
    sred[wid][5] = sgn * g3;
  }
  __syncthreads();
  if (tid < NQ) {
    const double s = sred[0][tid] + sred[1][tid] + sred[2][tid] + sred[3][tid];
    P[tid * NBLK + blockIdx.x] = s;
  }
}

__global__ __launch_bounds__(1024) void sig_final(const double* __restrict__ P,
                                                  float* __restrict__ out) {
  const int tid = threadIdx.x;
  double loc[NQ] = {0, 0, 0, 0, 0, 0};
  for (int i = tid; i < NBLK; i += 1024) {
#pragma unroll
    for (int q = 0; q < NQ; ++q) loc[q] += P[q * NBLK + i];
  }
#pragma unroll
  for (int q = 0; q < NQ; ++q)
#pragma unroll
    for (int o = 32; o; o >>= 1) loc[q] += __shfl_down(loc[q], o, 64);

  __shared__ double sred[16][NQ];
  const int lane = tid & 63, wid = tid >> 6;
  if (lane == 0)
#pragma unroll
    for (int q = 0; q < NQ; ++q) sred[wid][q] = loc[q];
  __syncthreads();
  if (tid == 0) {
    double Q[NQ];
#pragma unroll
    for (int q = 0; q < NQ; ++q) {
      double s = 0.;
      for (int v = 0; v < 16; ++v) s += sred[v][q];
      Q[q] = s;
    }
    const double n = (double)(T_LEN - 1), Bn = (double)B_ROWS;
    const double FA = Q[3] / Bn;
    const double FS3 = (Q[5] - Q[0] / n) / Bn;
    const double FS4 = 0.5 * (Q[4] + Q[1]) / Bn;
    const double FS6 = Q[1] / Bn;
    const double FS8 = Q[2] / Bn;
    const double o = FA * FA + FS3 * FS3 + FS4 * FS4 + FS6 * FS6 + FS8 * FS8;
    out[0] = (float)o;
  }
}

extern "C" void kernel_launch(void* const* d_in, const int* in_sizes, int n_in,
                              void* d_out, int out_size, void* d_ws, size_t ws_size,
                              hipStream_t stream) {
  const float* real = (const float*)d_in[0];
  const float* gen = (const float*)d_in[1];
  double* P = (double*)d_ws;            // NQ * NBLK * 8 = 96 KB
  float* out = (float*)d_out;

  sig_stream<<<NBLK, 256, 0, stream>>>(real, gen, P);
  sig_final<<<1, 1024, 0, stream>>>(P, out);
}